// Round 9
// baseline (177.405 us; speedup 1.0000x reference)
//
#include <hip/hip_runtime.h>
#include <math.h>

#define NPART 2048
#define DT 0.016f
#define MARGIN_EPS 2e-3f

typedef _Float16 f16x8 __attribute__((ext_vector_type(8)));     // 8 f16 = 4 VGPRs (MFMA A/B)
typedef __attribute__((ext_vector_type(16))) float f32x16;      // MFMA C/D accumulator

#define MFMA(A, B, C) __builtin_amdgcn_mfma_f32_32x32x16_f16((A), (B), (C), 0, 0, 0)

// f32 pair -> packed f16x2 dword, round-to-nearest
__device__ inline unsigned pk16(float lo, float hi) {
    union { _Float16 h[2]; unsigned u; } x;
    x.h[0] = (_Float16)lo; x.h[1] = (_Float16)hi;
    return x.u;
}
// v_permlane32_swap_b32 D,S: D' = [D.lo32, S.lo32]; S' = [D.hi32, S.hi32]
__device__ inline void swap32(unsigned &x, unsigned &y) {
    asm("v_permlane32_swap_b32 %0, %1" : "+v"(x), "+v"(y));
}
__device__ inline f16x8 mk8(unsigned a, unsigned b, unsigned c, unsigned d) {
    union { unsigned u[4]; f16x8 s; } u;
    u.u[0] = a; u.u[1] = b; u.u[2] = c; u.u[3] = d;
    return u.s;
}
__device__ inline f16x8 pack8(const float f[8]) {
    return mk8(pk16(f[0], f[1]), pk16(f[2], f[3]), pk16(f[4], f[5]), pk16(f[6], f[7]));
}

// tanh(x)*10 = 10 - 20/(exp2(x*2*log2e)+1); v_exp/v_rcp 1-ulp, limits exact.
__device__ inline float tanh10(float x) {
    float e;
    asm("v_exp_f32 %0, %1" : "=v"(e) : "v"(x * 2.885390081777927f));
    float r;
    asm("v_rcp_f32 %0, %1" : "=v"(r) : "v"(e + 1.0f));
    return fmaf(-20.f, r, 10.f);
}

// D-tile (32 neurons x 32 edges) -> two B k-groups (k = neuron), with relu.
// Verified layout: C/D row = (reg&3)+8*(reg>>2)+4*(lane>>5), col = lane&31;
// B: col = lane&31, k = 8*(lane>>5)+elem.
__device__ inline void d2b(const f32x16 &d, f16x8 &blo, f16x8 &bhi) {
    float r[16];
#pragma unroll
    for (int t = 0; t < 16; ++t) r[t] = fmaxf(d[t], 0.f);
    unsigned p01 = pk16(r[0], r[1]),  p23 = pk16(r[2], r[3]);
    unsigned p45 = pk16(r[4], r[5]),  p67 = pk16(r[6], r[7]);
    swap32(p01, p45);
    swap32(p23, p67);
    blo = mk8(p01, p23, p45, p67);
    unsigned q01 = pk16(r[8], r[9]),   q23 = pk16(r[10], r[11]);
    unsigned q45 = pk16(r[12], r[13]), q67 = pk16(r[14], r[15]);
    swap32(q01, q45);
    swap32(q23, q67);
    bhi = mk8(q01, q23, q45, q67);
}

// Split version: relu'd D-tile -> hi fragments (h0,h1) and lo fragments (l0,l1),
// value = hi + lo to ~2^-22 relative. Same swap pattern as d2b for each part.
__device__ inline void d2b_split(const f32x16 &d, f16x8 &h0, f16x8 &h1, f16x8 &l0, f16x8 &l1) {
    float r[16];
#pragma unroll
    for (int t = 0; t < 16; ++t) r[t] = fmaxf(d[t], 0.f);
    unsigned ph[8], pl[8];
#pragma unroll
    for (int q = 0; q < 8; ++q) {
        const float a = r[2 * q], b = r[2 * q + 1];
        const _Float16 ha = (_Float16)a, hb = (_Float16)b;
        union { _Float16 h[2]; unsigned u; } up;
        up.h[0] = ha; up.h[1] = hb;
        ph[q] = up.u;
        union { _Float16 h[2]; unsigned u; } ul;
        ul.h[0] = (_Float16)(a - (float)ha); ul.h[1] = (_Float16)(b - (float)hb);
        pl[q] = ul.u;
    }
    swap32(ph[0], ph[2]); swap32(ph[1], ph[3]);
    h0 = mk8(ph[0], ph[1], ph[2], ph[3]);
    swap32(ph[4], ph[6]); swap32(ph[5], ph[7]);
    h1 = mk8(ph[4], ph[5], ph[6], ph[7]);
    swap32(pl[0], pl[2]); swap32(pl[1], pl[3]);
    l0 = mk8(pl[0], pl[1], pl[2], pl[3]);
    swap32(pl[4], pl[6]); swap32(pl[5], pl[7]);
    l1 = mk8(pl[4], pl[5], pl[6], pl[7]);
}

// ============================ MAIN KERNEL (fast fp16) ======================================
// One block per particle i; 4 waves; wave w covers j-tiles w*16 .. w*16+15 (32 j per tile).
// Writes outputs + pre-clamp npy margin to ws[i] for the repair pass.
__global__ __launch_bounds__(256) void particle_step_kernel(
    const float* __restrict__ ext,  const float* __restrict__ pos,
    const float* __restrict__ vel,  const float* __restrict__ mass,
    const float* __restrict__ elast, const float* __restrict__ fric,
    const float* __restrict__ W1, const float* __restrict__ b1,
    const float* __restrict__ W2, const float* __restrict__ b2,
    const float* __restrict__ W3, const float* __restrict__ b3,
    const float* __restrict__ W4, const float* __restrict__ b4,
    float* __restrict__ out, float* __restrict__ ws)
{
    const int l = threadIdx.x & 63;
    const int c = l & 31;
    const int h = l >> 5;
    const int w = threadIdx.x >> 6;
    const int i = blockIdx.x;

    // weight A-fragments (A[m][k] = W[k][m]; bias in gate k-slot)
    f16x8 a1[2], a2[2][5], a3[5], a4[3];
#pragma unroll
    for (int mt = 0; mt < 2; ++mt) {
        const int m = c + 32 * mt;
        float f[8];
        if (h == 0) {
#pragma unroll
            for (int e = 0; e < 8; ++e) f[e] = W1[e * 64 + m];
        } else {
            f[0] = b1[m];
#pragma unroll
            for (int e = 1; e < 8; ++e) f[e] = 0.f;
        }
        a1[mt] = pack8(f);
    }
#pragma unroll
    for (int mt = 0; mt < 2; ++mt) {
        const int m = c + 32 * mt;
#pragma unroll
        for (int kg = 0; kg < 4; ++kg) {
            float f[8];
#pragma unroll
            for (int e = 0; e < 8; ++e) f[e] = W2[(kg * 16 + 8 * h + e) * 64 + m];
            a2[mt][kg] = pack8(f);
        }
        float f[8];
        f[0] = (h == 0) ? b2[m] : 0.f;
#pragma unroll
        for (int e = 1; e < 8; ++e) f[e] = 0.f;
        a2[mt][4] = pack8(f);
    }
#pragma unroll
    for (int kg = 0; kg < 4; ++kg) {
        float f[8];
#pragma unroll
        for (int e = 0; e < 8; ++e) f[e] = W3[(kg * 16 + 8 * h + e) * 32 + c];
        a3[kg] = pack8(f);
    }
    {
        float f[8];
        f[0] = (h == 0) ? b3[c] : 0.f;
#pragma unroll
        for (int e = 1; e < 8; ++e) f[e] = 0.f;
        a3[4] = pack8(f);
    }
#pragma unroll
    for (int kg = 0; kg < 2; ++kg) {
        float f[8];
#pragma unroll
        for (int e = 0; e < 8; ++e) f[e] = (c < 3) ? W4[(kg * 16 + 8 * h + e) * 3 + c] : 0.f;
        a4[kg] = pack8(f);
    }
    {
        float f[8];
        f[0] = (h == 0 && c < 3) ? b4[c] : 0.f;
#pragma unroll
        for (int e = 1; e < 8; ++e) f[e] = 0.f;
        a4[2] = pack8(f);
    }

    const f16x8 bgate = mk8((l < 32) ? 0x00003C00u : 0u, 0u, 0u, 0u);
    const f32x16 z = {};

    const float pix = pos[3 * i], piy = pos[3 * i + 1], piz = pos[3 * i + 2];
    const float vix = vel[3 * i], viy = vel[3 * i + 1], viz = vel[3 * i + 2];
    const float mi = mass[i];

    float Fx = 0.f, Fy = 0.f, Fz = 0.f;

    for (int t = 0; t < 16; ++t) {
        const int j = (w * 16 + t) * 32 + c;

        const float pjx = pos[3 * j], pjy = pos[3 * j + 1], pjz = pos[3 * j + 2];
        const float vjx = vel[3 * j], vjy = vel[3 * j + 1], vjz = vel[3 * j + 2];
        const float mj = mass[j];
        const float rx = pjx - pix, ry = pjy - piy, rz = pjz - piz;
        const float sx = vjx - vix, sy = vjy - viy, sz = vjz - viz;
        const float d2 = rx * rx + ry * ry + rz * rz;
        const float dist = __builtin_amdgcn_sqrtf(d2);
        const float ratio = mi * __builtin_amdgcn_rcpf(mj);
        const float sel = (l < 32 && dist < 1.0f && j != i) ? 1.0f : 0.0f;

        const unsigned d0 = pk16(rx, ry), d1 = pk16(rz, sx);
        const unsigned d2p = pk16(sy, sz), d3 = pk16(dist, ratio);
        const f16x8 bf = mk8((l < 32) ? d0 : 0x00003C00u,
                             (l < 32) ? d1 : 0u,
                             (l < 32) ? d2p : 0u,
                             (l < 32) ? d3 : 0u);

        f32x16 acc0 = MFMA(a1[0], bf, z);
        f32x16 acc1 = MFMA(a1[1], bf, z);

        f16x8 bn[4];
        d2b(acc0, bn[0], bn[1]);
        d2b(acc1, bn[2], bn[3]);

        acc0 = MFMA(a2[0][0], bn[0], z);
        acc1 = MFMA(a2[1][0], bn[0], z);
        acc0 = MFMA(a2[0][1], bn[1], acc0);
        acc1 = MFMA(a2[1][1], bn[1], acc1);
        acc0 = MFMA(a2[0][2], bn[2], acc0);
        acc1 = MFMA(a2[1][2], bn[2], acc1);
        acc0 = MFMA(a2[0][3], bn[3], acc0);
        acc1 = MFMA(a2[1][3], bn[3], acc1);
        acc0 = MFMA(a2[0][4], bgate, acc0);
        acc1 = MFMA(a2[1][4], bgate, acc1);

        d2b(acc0, bn[0], bn[1]);
        d2b(acc1, bn[2], bn[3]);

        f32x16 acc3 = MFMA(a3[0], bn[0], z);
        acc3 = MFMA(a3[1], bn[1], acc3);
        acc3 = MFMA(a3[2], bn[2], acc3);
        acc3 = MFMA(a3[3], bn[3], acc3);
        acc3 = MFMA(a3[4], bgate, acc3);

        f16x8 b4lo, b4hi;
        d2b(acc3, b4lo, b4hi);

        f32x16 o = MFMA(a4[0], b4lo, z);
        o = MFMA(a4[1], b4hi, o);
        o = MFMA(a4[2], bgate, o);

        Fx = fmaf(sel, tanh10(o[0]), Fx);
        Fy = fmaf(sel, tanh10(o[1]), Fy);
        Fz = fmaf(sel, tanh10(o[2]), Fz);
    }

#pragma unroll
    for (int off = 1; off < 64; off <<= 1) {
        Fx += __shfl_xor(Fx, off);
        Fy += __shfl_xor(Fy, off);
        Fz += __shfl_xor(Fz, off);
    }
    __shared__ float red[4][3];
    if ((threadIdx.x & 63) == 0) { red[w][0] = Fx; red[w][1] = Fy; red[w][2] = Fz; }
    __syncthreads();

    if (threadIdx.x == 0) {
        float FX = red[0][0] + red[1][0] + red[2][0] + red[3][0];
        float FY = red[0][1] + red[1][1] + red[2][1] + red[3][1];
        float FZ = red[0][2] + red[1][2] + red[2][2] + red[3][2];

        FX += ext[3 * i + 0];
        FY += ext[3 * i + 1] + (-9.8f) * mi;
        FZ += ext[3 * i + 2];

        const float inv_m = 1.0f / mi;
        float nvx = vix + FX * inv_m * DT;
        float nvy = viy + FY * inv_m * DT;
        float nvz = viz + FZ * inv_m * DT;

        const float speed = sqrtf(nvx * nvx + nvy * nvy + nvz * nvz);
        if (speed > 0.1f) {
            const float s = fric[i] * DT;
            nvx -= nvx * s;
            nvy -= nvy * s;
            nvz -= nvz * s;
        }

        float npx = pix + nvx * DT;
        float npy = piy + nvy * DT;
        float npz = piz + nvz * DT;

        ws[i] = npy;   // pre-clamp collision margin for the repair pass

        if (npy < 0.0f) {
            npy = 0.0f;
            nvy = -nvy * elast[i];
        }

        out[3 * i + 0] = npx;
        out[3 * i + 1] = npy;
        out[3 * i + 2] = npz;
        out[NPART * 3 + 3 * i + 0] = nvx;
        out[NPART * 3 + 3 * i + 1] = nvy;
        out[NPART * 3 + 3 * i + 2] = nvz;
    }
}

// ========================= REPAIR KERNEL (split fp16 ~ fp32) ===============================
// Runs only for particles whose pre-clamp npy is within MARGIN_EPS of the collision branch.
// W = Wh+Wl, h = hh+hl; f16xf16 products are exact in fp32 -> ~2^-22 effective precision.
__global__ __launch_bounds__(256, 1) void particle_fix_kernel(
    const float* __restrict__ ext,  const float* __restrict__ pos,
    const float* __restrict__ vel,  const float* __restrict__ mass,
    const float* __restrict__ elast, const float* __restrict__ fric,
    const float* __restrict__ W1, const float* __restrict__ b1,
    const float* __restrict__ W2, const float* __restrict__ b2,
    const float* __restrict__ W3, const float* __restrict__ b3,
    const float* __restrict__ W4, const float* __restrict__ b4,
    float* __restrict__ out, const float* __restrict__ ws)
{
    const int i = blockIdx.x;
    if (fabsf(ws[i]) >= MARGIN_EPS) return;   // uniform early exit

    const int l = threadIdx.x & 63;
    const int c = l & 31;
    const int h = l >> 5;
    const int w = threadIdx.x >> 6;

    // ---- split weight fragments ----
    f16x8 a1h[2], a1l[2];                 // L1: [W1h;W1h] and [W1l;W1l] (k halves duplicated)
    f16x8 a2h[2][4], a2l[2][4];
    f16x8 a3h[4], a3l[4];
    f16x8 a4h[2], a4l[2];
#pragma unroll
    for (int mt = 0; mt < 2; ++mt) {
        const int m = c + 32 * mt;
        float fh[8], fl[8];
#pragma unroll
        for (int e = 0; e < 8; ++e) {
            const float v = W1[e * 64 + m];
            const float vh = (float)(_Float16)v;
            fh[e] = vh; fl[e] = v - vh;
        }
        a1h[mt] = pack8(fh); a1l[mt] = pack8(fl);
    }
#pragma unroll
    for (int mt = 0; mt < 2; ++mt) {
        const int m = c + 32 * mt;
#pragma unroll
        for (int kg = 0; kg < 4; ++kg) {
            float fh[8], fl[8];
#pragma unroll
            for (int e = 0; e < 8; ++e) {
                const float v = W2[(kg * 16 + 8 * h + e) * 64 + m];
                const float vh = (float)(_Float16)v;
                fh[e] = vh; fl[e] = v - vh;
            }
            a2h[mt][kg] = pack8(fh); a2l[mt][kg] = pack8(fl);
        }
    }
#pragma unroll
    for (int kg = 0; kg < 4; ++kg) {
        float fh[8], fl[8];
#pragma unroll
        for (int e = 0; e < 8; ++e) {
            const float v = W3[(kg * 16 + 8 * h + e) * 32 + c];
            const float vh = (float)(_Float16)v;
            fh[e] = vh; fl[e] = v - vh;
        }
        a3h[kg] = pack8(fh); a3l[kg] = pack8(fl);
    }
#pragma unroll
    for (int kg = 0; kg < 2; ++kg) {
        float fh[8], fl[8];
#pragma unroll
        for (int e = 0; e < 8; ++e) {
            const float v = (c < 3) ? W4[(kg * 16 + 8 * h + e) * 3 + c] : 0.f;
            const float vh = (float)(_Float16)v;
            fh[e] = vh; fl[e] = v - vh;
        }
        a4h[kg] = pack8(fh); a4l[kg] = pack8(fl);
    }

    // ---- exact biases as fp32 C-operand vectors: C[reg] = b[row(reg,h)] ----
    f32x16 cb1a, cb1b, cb2a, cb2b, cb3, cb4;
#pragma unroll
    for (int t = 0; t < 16; ++t) {
        const int row = (t & 3) + 8 * (t >> 2) + 4 * h;
        cb1a[t] = b1[row];       cb1b[t] = b1[32 + row];
        cb2a[t] = b2[row];       cb2b[t] = b2[32 + row];
        cb3[t]  = b3[row];
        cb4[t]  = (row < 3) ? b4[row] : 0.f;
    }

    const float pix = pos[3 * i], piy = pos[3 * i + 1], piz = pos[3 * i + 2];
    const float vix = vel[3 * i], viy = vel[3 * i + 1], viz = vel[3 * i + 2];
    const float mi = mass[i];

    float Fx = 0.f, Fy = 0.f, Fz = 0.f;

    for (int t = 0; t < 16; ++t) {
        const int j = (w * 16 + t) * 32 + c;

        const float pjx = pos[3 * j], pjy = pos[3 * j + 1], pjz = pos[3 * j + 2];
        const float vjx = vel[3 * j], vjy = vel[3 * j + 1], vjz = vel[3 * j + 2];
        const float mj = mass[j];
        const float rx = pjx - pix, ry = pjy - piy, rz = pjz - piz;
        const float sx = vjx - vix, sy = vjy - viy, sz = vjz - viz;
        const float d2 = rx * rx + ry * ry + rz * rz;
        const float dist = sqrtf(d2);
        const float ratio = mi / mj;
        const float sel = (l < 32 && dist < 1.0f && j != i) ? 1.0f : 0.0f;

        // feature split: lanes<32 carry hi (k0-7), lanes>=32 carry lo (k8-15)
        float f8v[8] = { rx, ry, rz, sx, sy, sz, dist, ratio };
        float fh[8], fl[8];
#pragma unroll
        for (int e = 0; e < 8; ++e) {
            const float vh = (float)(_Float16)f8v[e];
            fh[e] = vh; fl[e] = f8v[e] - vh;
        }
        const f16x8 bfh = pack8(fh), bfl = pack8(fl);
        const f16x8 bf = (l < 32) ? bfh : bfl;

        // ---- L1: (W1h+W1l)·(fh+fl), bias exact in C ----
        f32x16 acc0 = MFMA(a1h[0], bf, cb1a);
        acc0 = MFMA(a1l[0], bf, acc0);
        f32x16 acc1 = MFMA(a1h[1], bf, cb1b);
        acc1 = MFMA(a1l[1], bf, acc1);

        // ---- h1 -> split B fragments ----
        f16x8 bh0, bh1, bh2, bh3, bl0, bl1, bl2, bl3;
        d2b_split(acc0, bh0, bh1, bl0, bl1);
        d2b_split(acc1, bh2, bh3, bl2, bl3);

        // ---- L2: Wh·hh + Wh·hl + Wl·hh per m-tile ----
        acc0 = MFMA(a2h[0][0], bh0, cb2a);
        acc0 = MFMA(a2h[0][1], bh1, acc0);
        acc0 = MFMA(a2h[0][2], bh2, acc0);
        acc0 = MFMA(a2h[0][3], bh3, acc0);
        acc0 = MFMA(a2h[0][0], bl0, acc0);
        acc0 = MFMA(a2h[0][1], bl1, acc0);
        acc0 = MFMA(a2h[0][2], bl2, acc0);
        acc0 = MFMA(a2h[0][3], bl3, acc0);
        acc0 = MFMA(a2l[0][0], bh0, acc0);
        acc0 = MFMA(a2l[0][1], bh1, acc0);
        acc0 = MFMA(a2l[0][2], bh2, acc0);
        acc0 = MFMA(a2l[0][3], bh3, acc0);
        acc1 = MFMA(a2h[1][0], bh0, cb2b);
        acc1 = MFMA(a2h[1][1], bh1, acc1);
        acc1 = MFMA(a2h[1][2], bh2, acc1);
        acc1 = MFMA(a2h[1][3], bh3, acc1);
        acc1 = MFMA(a2h[1][0], bl0, acc1);
        acc1 = MFMA(a2h[1][1], bl1, acc1);
        acc1 = MFMA(a2h[1][2], bl2, acc1);
        acc1 = MFMA(a2h[1][3], bl3, acc1);
        acc1 = MFMA(a2l[1][0], bh0, acc1);
        acc1 = MFMA(a2l[1][1], bh1, acc1);
        acc1 = MFMA(a2l[1][2], bh2, acc1);
        acc1 = MFMA(a2l[1][3], bh3, acc1);

        // ---- h2 -> split B ----
        d2b_split(acc0, bh0, bh1, bl0, bl1);
        d2b_split(acc1, bh2, bh3, bl2, bl3);

        // ---- L3 ----
        f32x16 acc3 = MFMA(a3h[0], bh0, cb3);
        acc3 = MFMA(a3h[1], bh1, acc3);
        acc3 = MFMA(a3h[2], bh2, acc3);
        acc3 = MFMA(a3h[3], bh3, acc3);
        acc3 = MFMA(a3h[0], bl0, acc3);
        acc3 = MFMA(a3h[1], bl1, acc3);
        acc3 = MFMA(a3h[2], bl2, acc3);
        acc3 = MFMA(a3h[3], bl3, acc3);
        acc3 = MFMA(a3l[0], bh0, acc3);
        acc3 = MFMA(a3l[1], bh1, acc3);
        acc3 = MFMA(a3l[2], bh2, acc3);
        acc3 = MFMA(a3l[3], bh3, acc3);

        // ---- h3 -> split B ----
        f16x8 th0, th1, tl0, tl1;
        d2b_split(acc3, th0, th1, tl0, tl1);

        // ---- L4 ----
        f32x16 o = MFMA(a4h[0], th0, cb4);
        o = MFMA(a4h[1], th1, o);
        o = MFMA(a4h[0], tl0, o);
        o = MFMA(a4h[1], tl1, o);
        o = MFMA(a4l[0], th0, o);
        o = MFMA(a4l[1], th1, o);

        Fx = fmaf(sel, tanhf(o[0]) * 10.f, Fx);
        Fy = fmaf(sel, tanhf(o[1]) * 10.f, Fy);
        Fz = fmaf(sel, tanhf(o[2]) * 10.f, Fz);
    }

#pragma unroll
    for (int off = 1; off < 64; off <<= 1) {
        Fx += __shfl_xor(Fx, off);
        Fy += __shfl_xor(Fy, off);
        Fz += __shfl_xor(Fz, off);
    }
    __shared__ float red[4][3];
    if ((threadIdx.x & 63) == 0) { red[w][0] = Fx; red[w][1] = Fy; red[w][2] = Fz; }
    __syncthreads();

    if (threadIdx.x == 0) {
        float FX = red[0][0] + red[1][0] + red[2][0] + red[3][0];
        float FY = red[0][1] + red[1][1] + red[2][1] + red[3][1];
        float FZ = red[0][2] + red[1][2] + red[2][2] + red[3][2];

        FX += ext[3 * i + 0];
        FY += ext[3 * i + 1] + (-9.8f) * mi;
        FZ += ext[3 * i + 2];

        const float inv_m = 1.0f / mi;
        float nvx = vix + FX * inv_m * DT;
        float nvy = viy + FY * inv_m * DT;
        float nvz = viz + FZ * inv_m * DT;

        const float speed = sqrtf(nvx * nvx + nvy * nvy + nvz * nvz);
        if (speed > 0.1f) {
            const float s = fric[i] * DT;
            nvx -= nvx * s;
            nvy -= nvy * s;
            nvz -= nvz * s;
        }

        float npx = pix + nvx * DT;
        float npy = piy + nvy * DT;
        float npz = piz + nvz * DT;

        if (npy < 0.0f) {
            npy = 0.0f;
            nvy = -nvy * elast[i];
        }

        out[3 * i + 0] = npx;
        out[3 * i + 1] = npy;
        out[3 * i + 2] = npz;
        out[NPART * 3 + 3 * i + 0] = nvx;
        out[NPART * 3 + 3 * i + 1] = nvy;
        out[NPART * 3 + 3 * i + 2] = nvz;
    }
}

extern "C" void kernel_launch(void* const* d_in, const int* in_sizes, int n_in,
                              void* d_out, int out_size, void* d_ws, size_t ws_size,
                              hipStream_t stream) {
    const float* ext   = (const float*)d_in[0];
    const float* pos   = (const float*)d_in[1];
    const float* vel   = (const float*)d_in[2];
    const float* mass  = (const float*)d_in[3];
    const float* elast = (const float*)d_in[4];
    const float* fric  = (const float*)d_in[5];
    const float* W1 = (const float*)d_in[6];
    const float* b1 = (const float*)d_in[7];
    const float* W2 = (const float*)d_in[8];
    const float* b2 = (const float*)d_in[9];
    const float* W3 = (const float*)d_in[10];
    const float* b3 = (const float*)d_in[11];
    const float* W4 = (const float*)d_in[12];
    const float* b4 = (const float*)d_in[13];
    float* out = (float*)d_out;
    float* wsf = (float*)d_ws;

    particle_step_kernel<<<NPART, 256, 0, stream>>>(
        ext, pos, vel, mass, elast, fric,
        W1, b1, W2, b2, W3, b3, W4, b4, out, wsf);
    particle_fix_kernel<<<NPART, 256, 0, stream>>>(
        ext, pos, vel, mass, elast, fric,
        W1, b1, W2, b2, W3, b3, W4, b4, out, wsf);
}

// Round 10
// 154.581 us; speedup vs baseline: 1.1477x; 1.1477x over previous
//
#include <hip/hip_runtime.h>
#include <math.h>

#define NPART 2048
#define DT 0.016f
#define MARGIN_EPS 2e-3f

typedef _Float16 f16x8 __attribute__((ext_vector_type(8)));     // 8 f16 = 4 VGPRs (MFMA A/B)
typedef __attribute__((ext_vector_type(16))) float f32x16;      // MFMA C/D accumulator

#define MFMA(A, B, C) __builtin_amdgcn_mfma_f32_32x32x16_f16((A), (B), (C), 0, 0, 0)

// f32 pair -> packed f16x2 dword, round-to-nearest
__device__ inline unsigned pk16(float lo, float hi) {
    union { _Float16 h[2]; unsigned u; } x;
    x.h[0] = (_Float16)lo; x.h[1] = (_Float16)hi;
    return x.u;
}
// packed f16 relu: v_pk_max_f16 d,x,+0. For x>0 returns x; for x<=0 (incl -0, -inf)
// returns +0 (S1 on compare-false). Value-identical to fmaxf-then-convert in ALL cases.
__device__ inline unsigned pk_relu(unsigned x) {
    unsigned r; unsigned z = 0;
    asm("v_pk_max_f16 %0, %1, %2" : "=v"(r) : "v"(x), "v"(z));
    return r;
}
// v_permlane32_swap_b32 D,S: D' = [D.lo32, S.lo32]; S' = [D.hi32, S.hi32]
__device__ inline void swap32(unsigned &x, unsigned &y) {
    asm("v_permlane32_swap_b32 %0, %1" : "+v"(x), "+v"(y));
}
__device__ inline f16x8 mk8(unsigned a, unsigned b, unsigned c, unsigned d) {
    union { unsigned u[4]; f16x8 s; } u;
    u.u[0] = a; u.u[1] = b; u.u[2] = c; u.u[3] = d;
    return u.s;
}
__device__ inline f16x8 pack8(const float f[8]) {
    return mk8(pk16(f[0], f[1]), pk16(f[2], f[3]), pk16(f[4], f[5]), pk16(f[6], f[7]));
}

// tanh(x)*10 = 10 - 20/(exp2(x*2*log2e)+1); v_exp/v_rcp 1-ulp, limits exact.
__device__ inline float tanh10(float x) {
    float e;
    asm("v_exp_f32 %0, %1" : "=v"(e) : "v"(x * 2.885390081777927f));
    float r;
    asm("v_rcp_f32 %0, %1" : "=v"(r) : "v"(e + 1.0f));
    return fmaf(-20.f, r, 10.f);
}

// D-tile (32 neurons x 32 edges) -> two B k-groups (k = neuron), with relu.
// Verified layout: C/D row = (reg&3)+8*(reg>>2)+4*(lane>>5), col = lane&31;
// B: col = lane&31, k = 8*(lane>>5)+elem.
// Relu applied post-pack via pk_relu (bit-identical to fmaxf-then-pack; saves 8 VALU).
__device__ inline void d2b(const f32x16 &d, f16x8 &blo, f16x8 &bhi) {
    unsigned p[8];
#pragma unroll
    for (int q = 0; q < 8; ++q) p[q] = pk_relu(pk16(d[2 * q], d[2 * q + 1]));
    swap32(p[0], p[2]);
    swap32(p[1], p[3]);
    blo = mk8(p[0], p[1], p[2], p[3]);
    swap32(p[4], p[6]);
    swap32(p[5], p[7]);
    bhi = mk8(p[4], p[5], p[6], p[7]);
}

// Split version: relu'd D-tile -> hi fragments (h0,h1) and lo fragments (l0,l1),
// value = hi + lo to ~2^-22 relative. Same swap pattern as d2b for each part.
// (Repair path: UNCHANGED from the verified round-5/9 source.)
__device__ inline void d2b_split(const f32x16 &d, f16x8 &h0, f16x8 &h1, f16x8 &l0, f16x8 &l1) {
    float r[16];
#pragma unroll
    for (int t = 0; t < 16; ++t) r[t] = fmaxf(d[t], 0.f);
    unsigned ph[8], pl[8];
#pragma unroll
    for (int q = 0; q < 8; ++q) {
        const float a = r[2 * q], b = r[2 * q + 1];
        const _Float16 ha = (_Float16)a, hb = (_Float16)b;
        union { _Float16 h[2]; unsigned u; } up;
        up.h[0] = ha; up.h[1] = hb;
        ph[q] = up.u;
        union { _Float16 h[2]; unsigned u; } ul;
        ul.h[0] = (_Float16)(a - (float)ha); ul.h[1] = (_Float16)(b - (float)hb);
        pl[q] = ul.u;
    }
    swap32(ph[0], ph[2]); swap32(ph[1], ph[3]);
    h0 = mk8(ph[0], ph[1], ph[2], ph[3]);
    swap32(ph[4], ph[6]); swap32(ph[5], ph[7]);
    h1 = mk8(ph[4], ph[5], ph[6], ph[7]);
    swap32(pl[0], pl[2]); swap32(pl[1], pl[3]);
    l0 = mk8(pl[0], pl[1], pl[2], pl[3]);
    swap32(pl[4], pl[6]); swap32(pl[5], pl[7]);
    l1 = mk8(pl[4], pl[5], pl[6], pl[7]);
}

// ============================ MAIN KERNEL (fast fp16) ======================================
// One block per particle i; 4 waves; wave w covers j-tiles w*16 .. w*16+15 (32 j per tile).
// Writes outputs + pre-clamp npy margin to ws[i] for the repair pass.
__global__ __launch_bounds__(256) void particle_step_kernel(
    const float* __restrict__ ext,  const float* __restrict__ pos,
    const float* __restrict__ vel,  const float* __restrict__ mass,
    const float* __restrict__ elast, const float* __restrict__ fric,
    const float* __restrict__ W1, const float* __restrict__ b1,
    const float* __restrict__ W2, const float* __restrict__ b2,
    const float* __restrict__ W3, const float* __restrict__ b3,
    const float* __restrict__ W4, const float* __restrict__ b4,
    float* __restrict__ out, float* __restrict__ ws)
{
    const int l = threadIdx.x & 63;
    const int c = l & 31;
    const int h = l >> 5;
    const int w = threadIdx.x >> 6;
    const int i = blockIdx.x;

    // weight A-fragments (A[m][k] = W[k][m]; bias in gate k-slot)
    f16x8 a1[2], a2[2][5], a3[5], a4[3];
#pragma unroll
    for (int mt = 0; mt < 2; ++mt) {
        const int m = c + 32 * mt;
        float f[8];
        if (h == 0) {
#pragma unroll
            for (int e = 0; e < 8; ++e) f[e] = W1[e * 64 + m];
        } else {
            f[0] = b1[m];
#pragma unroll
            for (int e = 1; e < 8; ++e) f[e] = 0.f;
        }
        a1[mt] = pack8(f);
    }
#pragma unroll
    for (int mt = 0; mt < 2; ++mt) {
        const int m = c + 32 * mt;
#pragma unroll
        for (int kg = 0; kg < 4; ++kg) {
            float f[8];
#pragma unroll
            for (int e = 0; e < 8; ++e) f[e] = W2[(kg * 16 + 8 * h + e) * 64 + m];
            a2[mt][kg] = pack8(f);
        }
        float f[8];
        f[0] = (h == 0) ? b2[m] : 0.f;
#pragma unroll
        for (int e = 1; e < 8; ++e) f[e] = 0.f;
        a2[mt][4] = pack8(f);
    }
#pragma unroll
    for (int kg = 0; kg < 4; ++kg) {
        float f[8];
#pragma unroll
        for (int e = 0; e < 8; ++e) f[e] = W3[(kg * 16 + 8 * h + e) * 32 + c];
        a3[kg] = pack8(f);
    }
    {
        float f[8];
        f[0] = (h == 0) ? b3[c] : 0.f;
#pragma unroll
        for (int e = 1; e < 8; ++e) f[e] = 0.f;
        a3[4] = pack8(f);
    }
#pragma unroll
    for (int kg = 0; kg < 2; ++kg) {
        float f[8];
#pragma unroll
        for (int e = 0; e < 8; ++e) f[e] = (c < 3) ? W4[(kg * 16 + 8 * h + e) * 3 + c] : 0.f;
        a4[kg] = pack8(f);
    }
    {
        float f[8];
        f[0] = (h == 0 && c < 3) ? b4[c] : 0.f;
#pragma unroll
        for (int e = 1; e < 8; ++e) f[e] = 0.f;
        a4[2] = pack8(f);
    }

    const f16x8 bgate = mk8((l < 32) ? 0x00003C00u : 0u, 0u, 0u, 0u);
    const f32x16 z = {};

    const float pix = pos[3 * i], piy = pos[3 * i + 1], piz = pos[3 * i + 2];
    const float vix = vel[3 * i], viy = vel[3 * i + 1], viz = vel[3 * i + 2];
    const float mi = mass[i];

    float Fx = 0.f, Fy = 0.f, Fz = 0.f;

    for (int t = 0; t < 16; ++t) {
        const int j = (w * 16 + t) * 32 + c;

        const float pjx = pos[3 * j], pjy = pos[3 * j + 1], pjz = pos[3 * j + 2];
        const float vjx = vel[3 * j], vjy = vel[3 * j + 1], vjz = vel[3 * j + 2];
        const float mj = mass[j];
        const float rx = pjx - pix, ry = pjy - piy, rz = pjz - piz;
        const float sx = vjx - vix, sy = vjy - viy, sz = vjz - viz;
        const float d2 = rx * rx + ry * ry + rz * rz;
        const float dist = __builtin_amdgcn_sqrtf(d2);
        const float ratio = mi * __builtin_amdgcn_rcpf(mj);
        const float sel = (l < 32 && dist < 1.0f && j != i) ? 1.0f : 0.0f;

        const unsigned d0 = pk16(rx, ry), d1 = pk16(rz, sx);
        const unsigned d2p = pk16(sy, sz), d3 = pk16(dist, ratio);
        const f16x8 bf = mk8((l < 32) ? d0 : 0x00003C00u,
                             (l < 32) ? d1 : 0u,
                             (l < 32) ? d2p : 0u,
                             (l < 32) ? d3 : 0u);

        f32x16 acc0 = MFMA(a1[0], bf, z);
        f32x16 acc1 = MFMA(a1[1], bf, z);

        f16x8 bn[4];
        d2b(acc0, bn[0], bn[1]);
        d2b(acc1, bn[2], bn[3]);

        acc0 = MFMA(a2[0][0], bn[0], z);
        acc1 = MFMA(a2[1][0], bn[0], z);
        acc0 = MFMA(a2[0][1], bn[1], acc0);
        acc1 = MFMA(a2[1][1], bn[1], acc1);
        acc0 = MFMA(a2[0][2], bn[2], acc0);
        acc1 = MFMA(a2[1][2], bn[2], acc1);
        acc0 = MFMA(a2[0][3], bn[3], acc0);
        acc1 = MFMA(a2[1][3], bn[3], acc1);
        acc0 = MFMA(a2[0][4], bgate, acc0);
        acc1 = MFMA(a2[1][4], bgate, acc1);

        d2b(acc0, bn[0], bn[1]);
        d2b(acc1, bn[2], bn[3]);

        f32x16 acc3 = MFMA(a3[0], bn[0], z);
        acc3 = MFMA(a3[1], bn[1], acc3);
        acc3 = MFMA(a3[2], bn[2], acc3);
        acc3 = MFMA(a3[3], bn[3], acc3);
        acc3 = MFMA(a3[4], bgate, acc3);

        f16x8 b4lo, b4hi;
        d2b(acc3, b4lo, b4hi);

        f32x16 o = MFMA(a4[0], b4lo, z);
        o = MFMA(a4[1], b4hi, o);
        o = MFMA(a4[2], bgate, o);

        Fx = fmaf(sel, tanh10(o[0]), Fx);
        Fy = fmaf(sel, tanh10(o[1]), Fy);
        Fz = fmaf(sel, tanh10(o[2]), Fz);
    }

#pragma unroll
    for (int off = 1; off < 64; off <<= 1) {
        Fx += __shfl_xor(Fx, off);
        Fy += __shfl_xor(Fy, off);
        Fz += __shfl_xor(Fz, off);
    }
    __shared__ float red[4][3];
    if ((threadIdx.x & 63) == 0) { red[w][0] = Fx; red[w][1] = Fy; red[w][2] = Fz; }
    __syncthreads();

    if (threadIdx.x == 0) {
        float FX = red[0][0] + red[1][0] + red[2][0] + red[3][0];
        float FY = red[0][1] + red[1][1] + red[2][1] + red[3][1];
        float FZ = red[0][2] + red[1][2] + red[2][2] + red[3][2];

        FX += ext[3 * i + 0];
        FY += ext[3 * i + 1] + (-9.8f) * mi;
        FZ += ext[3 * i + 2];

        const float inv_m = 1.0f / mi;
        float nvx = vix + FX * inv_m * DT;
        float nvy = viy + FY * inv_m * DT;
        float nvz = viz + FZ * inv_m * DT;

        const float speed = sqrtf(nvx * nvx + nvy * nvy + nvz * nvz);
        if (speed > 0.1f) {
            const float s = fric[i] * DT;
            nvx -= nvx * s;
            nvy -= nvy * s;
            nvz -= nvz * s;
        }

        float npx = pix + nvx * DT;
        float npy = piy + nvy * DT;
        float npz = piz + nvz * DT;

        ws[i] = npy;   // pre-clamp collision margin for the repair pass

        if (npy < 0.0f) {
            npy = 0.0f;
            nvy = -nvy * elast[i];
        }

        out[3 * i + 0] = npx;
        out[3 * i + 1] = npy;
        out[3 * i + 2] = npz;
        out[NPART * 3 + 3 * i + 0] = nvx;
        out[NPART * 3 + 3 * i + 1] = nvy;
        out[NPART * 3 + 3 * i + 2] = nvz;
    }
}

// ========================= REPAIR KERNEL (split fp16 ~ fp32) ===============================
// Runs only for particles whose pre-clamp npy is within MARGIN_EPS of the collision branch.
// W = Wh+Wl, h = hh+hl; f16xf16 products are exact in fp32 -> ~2^-22 effective precision.
// UNCHANGED from the verified round-5/9 source.
__global__ __launch_bounds__(256, 1) void particle_fix_kernel(
    const float* __restrict__ ext,  const float* __restrict__ pos,
    const float* __restrict__ vel,  const float* __restrict__ mass,
    const float* __restrict__ elast, const float* __restrict__ fric,
    const float* __restrict__ W1, const float* __restrict__ b1,
    const float* __restrict__ W2, const float* __restrict__ b2,
    const float* __restrict__ W3, const float* __restrict__ b3,
    const float* __restrict__ W4, const float* __restrict__ b4,
    float* __restrict__ out, const float* __restrict__ ws)
{
    const int i = blockIdx.x;
    if (fabsf(ws[i]) >= MARGIN_EPS) return;   // uniform early exit

    const int l = threadIdx.x & 63;
    const int c = l & 31;
    const int h = l >> 5;
    const int w = threadIdx.x >> 6;

    // ---- split weight fragments ----
    f16x8 a1h[2], a1l[2];                 // L1: [W1h;W1h] and [W1l;W1l] (k halves duplicated)
    f16x8 a2h[2][4], a2l[2][4];
    f16x8 a3h[4], a3l[4];
    f16x8 a4h[2], a4l[2];
#pragma unroll
    for (int mt = 0; mt < 2; ++mt) {
        const int m = c + 32 * mt;
        float fh[8], fl[8];
#pragma unroll
        for (int e = 0; e < 8; ++e) {
            const float v = W1[e * 64 + m];
            const float vh = (float)(_Float16)v;
            fh[e] = vh; fl[e] = v - vh;
        }
        a1h[mt] = pack8(fh); a1l[mt] = pack8(fl);
    }
#pragma unroll
    for (int mt = 0; mt < 2; ++mt) {
        const int m = c + 32 * mt;
#pragma unroll
        for (int kg = 0; kg < 4; ++kg) {
            float fh[8], fl[8];
#pragma unroll
            for (int e = 0; e < 8; ++e) {
                const float v = W2[(kg * 16 + 8 * h + e) * 64 + m];
                const float vh = (float)(_Float16)v;
                fh[e] = vh; fl[e] = v - vh;
            }
            a2h[mt][kg] = pack8(fh); a2l[mt][kg] = pack8(fl);
        }
    }
#pragma unroll
    for (int kg = 0; kg < 4; ++kg) {
        float fh[8], fl[8];
#pragma unroll
        for (int e = 0; e < 8; ++e) {
            const float v = W3[(kg * 16 + 8 * h + e) * 32 + c];
            const float vh = (float)(_Float16)v;
            fh[e] = vh; fl[e] = v - vh;
        }
        a3h[kg] = pack8(fh); a3l[kg] = pack8(fl);
    }
#pragma unroll
    for (int kg = 0; kg < 2; ++kg) {
        float fh[8], fl[8];
#pragma unroll
        for (int e = 0; e < 8; ++e) {
            const float v = (c < 3) ? W4[(kg * 16 + 8 * h + e) * 3 + c] : 0.f;
            const float vh = (float)(_Float16)v;
            fh[e] = vh; fl[e] = v - vh;
        }
        a4h[kg] = pack8(fh); a4l[kg] = pack8(fl);
    }

    // ---- exact biases as fp32 C-operand vectors: C[reg] = b[row(reg,h)] ----
    f32x16 cb1a, cb1b, cb2a, cb2b, cb3, cb4;
#pragma unroll
    for (int t = 0; t < 16; ++t) {
        const int row = (t & 3) + 8 * (t >> 2) + 4 * h;
        cb1a[t] = b1[row];       cb1b[t] = b1[32 + row];
        cb2a[t] = b2[row];       cb2b[t] = b2[32 + row];
        cb3[t]  = b3[row];
        cb4[t]  = (row < 3) ? b4[row] : 0.f;
    }

    const float pix = pos[3 * i], piy = pos[3 * i + 1], piz = pos[3 * i + 2];
    const float vix = vel[3 * i], viy = vel[3 * i + 1], viz = vel[3 * i + 2];
    const float mi = mass[i];

    float Fx = 0.f, Fy = 0.f, Fz = 0.f;

    for (int t = 0; t < 16; ++t) {
        const int j = (w * 16 + t) * 32 + c;

        const float pjx = pos[3 * j], pjy = pos[3 * j + 1], pjz = pos[3 * j + 2];
        const float vjx = vel[3 * j], vjy = vel[3 * j + 1], vjz = vel[3 * j + 2];
        const float mj = mass[j];
        const float rx = pjx - pix, ry = pjy - piy, rz = pjz - piz;
        const float sx = vjx - vix, sy = vjy - viy, sz = vjz - viz;
        const float d2 = rx * rx + ry * ry + rz * rz;
        const float dist = sqrtf(d2);
        const float ratio = mi / mj;
        const float sel = (l < 32 && dist < 1.0f && j != i) ? 1.0f : 0.0f;

        // feature split: lanes<32 carry hi (k0-7), lanes>=32 carry lo (k8-15)
        float f8v[8] = { rx, ry, rz, sx, sy, sz, dist, ratio };
        float fh[8], fl[8];
#pragma unroll
        for (int e = 0; e < 8; ++e) {
            const float vh = (float)(_Float16)f8v[e];
            fh[e] = vh; fl[e] = f8v[e] - vh;
        }
        const f16x8 bfh = pack8(fh), bfl = pack8(fl);
        const f16x8 bf = (l < 32) ? bfh : bfl;

        // ---- L1: (W1h+W1l)·(fh+fl), bias exact in C ----
        f32x16 acc0 = MFMA(a1h[0], bf, cb1a);
        acc0 = MFMA(a1l[0], bf, acc0);
        f32x16 acc1 = MFMA(a1h[1], bf, cb1b);
        acc1 = MFMA(a1l[1], bf, acc1);

        // ---- h1 -> split B fragments ----
        f16x8 bh0, bh1, bh2, bh3, bl0, bl1, bl2, bl3;
        d2b_split(acc0, bh0, bh1, bl0, bl1);
        d2b_split(acc1, bh2, bh3, bl2, bl3);

        // ---- L2: Wh·hh + Wh·hl + Wl·hh per m-tile ----
        acc0 = MFMA(a2h[0][0], bh0, cb2a);
        acc0 = MFMA(a2h[0][1], bh1, acc0);
        acc0 = MFMA(a2h[0][2], bh2, acc0);
        acc0 = MFMA(a2h[0][3], bh3, acc0);
        acc0 = MFMA(a2h[0][0], bl0, acc0);
        acc0 = MFMA(a2h[0][1], bl1, acc0);
        acc0 = MFMA(a2h[0][2], bl2, acc0);
        acc0 = MFMA(a2h[0][3], bl3, acc0);
        acc0 = MFMA(a2l[0][0], bh0, acc0);
        acc0 = MFMA(a2l[0][1], bh1, acc0);
        acc0 = MFMA(a2l[0][2], bh2, acc0);
        acc0 = MFMA(a2l[0][3], bh3, acc0);
        acc1 = MFMA(a2h[1][0], bh0, cb2b);
        acc1 = MFMA(a2h[1][1], bh1, acc1);
        acc1 = MFMA(a2h[1][2], bh2, acc1);
        acc1 = MFMA(a2h[1][3], bh3, acc1);
        acc1 = MFMA(a2h[1][0], bl0, acc1);
        acc1 = MFMA(a2h[1][1], bl1, acc1);
        acc1 = MFMA(a2h[1][2], bl2, acc1);
        acc1 = MFMA(a2h[1][3], bl3, acc1);
        acc1 = MFMA(a2l[1][0], bh0, acc1);
        acc1 = MFMA(a2l[1][1], bh1, acc1);
        acc1 = MFMA(a2l[1][2], bh2, acc1);
        acc1 = MFMA(a2l[1][3], bh3, acc1);

        // ---- h2 -> split B ----
        d2b_split(acc0, bh0, bh1, bl0, bl1);
        d2b_split(acc1, bh2, bh3, bl2, bl3);

        // ---- L3 ----
        f32x16 acc3 = MFMA(a3h[0], bh0, cb3);
        acc3 = MFMA(a3h[1], bh1, acc3);
        acc3 = MFMA(a3h[2], bh2, acc3);
        acc3 = MFMA(a3h[3], bh3, acc3);
        acc3 = MFMA(a3h[0], bl0, acc3);
        acc3 = MFMA(a3h[1], bl1, acc3);
        acc3 = MFMA(a3h[2], bl2, acc3);
        acc3 = MFMA(a3h[3], bl3, acc3);
        acc3 = MFMA(a3l[0], bh0, acc3);
        acc3 = MFMA(a3l[1], bh1, acc3);
        acc3 = MFMA(a3l[2], bh2, acc3);
        acc3 = MFMA(a3l[3], bh3, acc3);

        // ---- h3 -> split B ----
        f16x8 th0, th1, tl0, tl1;
        d2b_split(acc3, th0, th1, tl0, tl1);

        // ---- L4 ----
        f32x16 o = MFMA(a4h[0], th0, cb4);
        o = MFMA(a4h[1], th1, o);
        o = MFMA(a4h[0], tl0, o);
        o = MFMA(a4h[1], tl1, o);
        o = MFMA(a4l[0], th0, o);
        o = MFMA(a4l[1], th1, o);

        Fx = fmaf(sel, tanhf(o[0]) * 10.f, Fx);
        Fy = fmaf(sel, tanhf(o[1]) * 10.f, Fy);
        Fz = fmaf(sel, tanhf(o[2]) * 10.f, Fz);
    }

#pragma unroll
    for (int off = 1; off < 64; off <<= 1) {
        Fx += __shfl_xor(Fx, off);
        Fy += __shfl_xor(Fy, off);
        Fz += __shfl_xor(Fz, off);
    }
    __shared__ float red[4][3];
    if ((threadIdx.x & 63) == 0) { red[w][0] = Fx; red[w][1] = Fy; red[w][2] = Fz; }
    __syncthreads();

    if (threadIdx.x == 0) {
        float FX = red[0][0] + red[1][0] + red[2][0] + red[3][0];
        float FY = red[0][1] + red[1][1] + red[2][1] + red[3][1];
        float FZ = red[0][2] + red[1][2] + red[2][2] + red[3][2];

        FX += ext[3 * i + 0];
        FY += ext[3 * i + 1] + (-9.8f) * mi;
        FZ += ext[3 * i + 2];

        const float inv_m = 1.0f / mi;
        float nvx = vix + FX * inv_m * DT;
        float nvy = viy + FY * inv_m * DT;
        float nvz = viz + FZ * inv_m * DT;

        const float speed = sqrtf(nvx * nvx + nvy * nvy + nvz * nvz);
        if (speed > 0.1f) {
            const float s = fric[i] * DT;
            nvx -= nvx * s;
            nvy -= nvy * s;
            nvz -= nvz * s;
        }

        float npx = pix + nvx * DT;
        float npy = piy + nvy * DT;
        float npz = piz + nvz * DT;

        if (npy < 0.0f) {
            npy = 0.0f;
            nvy = -nvy * elast[i];
        }

        out[3 * i + 0] = npx;
        out[3 * i + 1] = npy;
        out[3 * i + 2] = npz;
        out[NPART * 3 + 3 * i + 0] = nvx;
        out[NPART * 3 + 3 * i + 1] = nvy;
        out[NPART * 3 + 3 * i + 2] = nvz;
    }
}

extern "C" void kernel_launch(void* const* d_in, const int* in_sizes, int n_in,
                              void* d_out, int out_size, void* d_ws, size_t ws_size,
                              hipStream_t stream) {
    const float* ext   = (const float*)d_in[0];
    const float* pos   = (const float*)d_in[1];
    const float* vel   = (const float*)d_in[2];
    const float* mass  = (const float*)d_in[3];
    const float* elast = (const float*)d_in[4];
    const float* fric  = (const float*)d_in[5];
    const float* W1 = (const float*)d_in[6];
    const float* b1 = (const float*)d_in[7];
    const float* W2 = (const float*)d_in[8];
    const float* b2 = (const float*)d_in[9];
    const float* W3 = (const float*)d_in[10];
    const float* b3 = (const float*)d_in[11];
    const float* W4 = (const float*)d_in[12];
    const float* b4 = (const float*)d_in[13];
    float* out = (float*)d_out;
    float* wsf = (float*)d_ws;

    particle_step_kernel<<<NPART, 256, 0, stream>>>(
        ext, pos, vel, mass, elast, fric,
        W1, b1, W2, b2, W3, b3, W4, b4, out, wsf);
    particle_fix_kernel<<<NPART, 256, 0, stream>>>(
        ext, pos, vel, mass, elast, fric,
        W1, b1, W2, b2, W3, b3, W4, b4, out, wsf);
}